// Round 2
// baseline (274.797 us; speedup 1.0000x reference)
//
#include <hip/hip_runtime.h>
#include <math.h>

#define N 4096
#define H 64
#define MAXDEG 128
#define NEG_SLOPE 0.2f
#define LN_EPS 1e-5f

__device__ __forceinline__ float wave_reduce_sum(float v) {
    #pragma unroll
    for (int m = 32; m >= 1; m >>= 1) v += __shfl_xor(v, m, 64);
    return v;
}
__device__ __forceinline__ float wave_reduce_max(float v) {
    #pragma unroll
    for (int m = 32; m >= 1; m >>= 1) v = fmaxf(v, __shfl_xor(v, m, 64));
    return v;
}

// Neighbor build: dest i's neighbors {j : adj[j][i] != 0} U {i}.
// float4 loads: thread t owns 4 consecutive columns (colgroup cg = t & 1023),
// band = t >> 10 covers rows band*64 .. band*64+63. Wave = 1 KB contiguous/instr.
__global__ void build_nbr(const float4* __restrict__ adj4,
                          int* __restrict__ cnt, int* __restrict__ nbr) {
    int t = blockIdx.x * blockDim.x + threadIdx.x;   // 65536 threads
    int cg = t & 1023;
    int band = t >> 10;
    int i0 = cg * 4;
    int jbase = band * 64;
    for (int jj = 0; jj < 64; ++jj) {
        int j = jbase + jj;
        float4 a = adj4[(size_t)j * 1024 + cg];
        if (a.x != 0.f || j == i0)     { int p = atomicAdd(&cnt[i0],   1); if (p < MAXDEG) nbr[ i0      * MAXDEG + p] = j; }
        if (a.y != 0.f || j == i0 + 1) { int p = atomicAdd(&cnt[i0+1], 1); if (p < MAXDEG) nbr[(i0 + 1) * MAXDEG + p] = j; }
        if (a.z != 0.f || j == i0 + 2) { int p = atomicAdd(&cnt[i0+2], 1); if (p < MAXDEG) nbr[(i0 + 2) * MAXDEG + p] = j; }
        if (a.w != 0.f || j == i0 + 3) { int p = atomicAdd(&cnt[i0+3], 1); if (p < MAXDEG) nbr[(i0 + 3) * MAXDEG + p] = j; }
    }
}

// Fused: embedding MLP (no nonlinearity) + layer-0 transform + scores.
__global__ void emb_tr0(const int* __restrict__ timestep,
                        const float* __restrict__ arr, const float* __restrict__ dep,
                        const float* __restrict__ hard,
                        const float* __restrict__ w1, const float* __restrict__ b1,
                        const float* __restrict__ w2, const float* __restrict__ b2,
                        const float* __restrict__ W0, const float* __restrict__ asrc,
                        const float* __restrict__ adst,
                        float* __restrict__ x, float* __restrict__ hw,
                        float* __restrict__ ssrc, float* __restrict__ sdst) {
    int wave = threadIdx.x >> 6;
    int lane = threadIdx.x & 63;
    int i = blockIdx.x * 4 + wave;
    float ts = (float)(*timestep);
    float pr = (ts - arr[i]) / (dep[i] - arr[i]);
    float hd = hard[i];
    float t = pr * w1[lane] + hd * w1[64 + lane] + b1[lane];
    float xv = b2[lane];
    #pragma unroll
    for (int k = 0; k < 64; ++k)
        xv += __shfl(t, k, 64) * w2[k * 64 + lane];
    x[i * 64 + lane] = xv;
    float acc = 0.f;
    #pragma unroll
    for (int k = 0; k < 64; ++k)
        acc += __shfl(xv, k, 64) * W0[k * 64 + lane];
    hw[i * 64 + lane] = acc;
    float s1 = wave_reduce_sum(acc * asrc[lane]);
    float s2 = wave_reduce_sum(acc * adst[lane]);
    if (lane == 0) { ssrc[i] = s1; sdst[i] = s2; }
}

// hw = h @ W ; ssrc = hw . asrc ; sdst = hw . adst.  Wave per row.
__global__ void gat_transform(const float* __restrict__ h, const float* __restrict__ W,
                              const float* __restrict__ asrc, const float* __restrict__ adst,
                              float* __restrict__ hw, float* __restrict__ ssrc,
                              float* __restrict__ sdst) {
    int wave = threadIdx.x >> 6;
    int lane = threadIdx.x & 63;
    int i = blockIdx.x * 4 + wave;
    float r = h[i * 64 + lane];
    float acc = 0.f;
    #pragma unroll
    for (int k = 0; k < 64; ++k)
        acc += __shfl(r, k, 64) * W[k * 64 + lane];
    hw[i * 64 + lane] = acc;
    float s1 = wave_reduce_sum(acc * asrc[lane]);
    float s2 = wave_reduce_sum(acc * adst[lane]);
    if (lane == 0) { ssrc[i] = s1; sdst[i] = s2; }
}

// Softmax over neighbors + aggregation. Indices/probs broadcast via shfl
// (already in registers from score phase) — only hw gathers touch memory.
__global__ void gat_aggregate(const float* __restrict__ hw, const float* __restrict__ ssrc,
                              const float* __restrict__ sdst, const int* __restrict__ nbr,
                              const int* __restrict__ cnt, const float* __restrict__ b,
                              float* __restrict__ hout, int do_relu) {
    int wave = threadIdx.x >> 6;
    int lane = threadIdx.x & 63;
    int i = blockIdx.x * 4 + wave;
    int deg = min(cnt[i], MAXDEG);
    float sd = sdst[i];
    int j0 = 0, j1 = 0;
    float e0 = -1e30f, e1 = -1e30f;
    if (lane < deg) {
        j0 = nbr[i * MAXDEG + lane];
        float v = ssrc[j0] + sd;
        e0 = v > 0.f ? v : NEG_SLOPE * v;
    }
    if (lane + 64 < deg) {
        j1 = nbr[i * MAXDEG + lane + 64];
        float v = ssrc[j1] + sd;
        e1 = v > 0.f ? v : NEG_SLOPE * v;
    }
    float m = wave_reduce_max(fmaxf(e0, e1));
    float p0 = (lane < deg) ? expf(e0 - m) : 0.f;
    float p1 = (lane + 64 < deg) ? expf(e1 - m) : 0.f;
    float Z = wave_reduce_sum(p0 + p1);
    float acc = 0.f;
    int d0 = min(deg, 64);
    #pragma unroll 4
    for (int n = 0; n < d0; ++n) {
        int   j = __shfl(j0, n, 64);
        float p = __shfl(p0, n, 64);
        acc += p * hw[j * 64 + lane];
    }
    for (int n = 64; n < deg; ++n) {
        int   j = __shfl(j1, n - 64, 64);
        float p = __shfl(p1, n - 64, 64);
        acc += p * hw[j * 64 + lane];
    }
    acc = acc / Z + b[lane];
    if (do_relu) acc = fmaxf(acc, 0.f);
    hout[i * 64 + lane] = acc;
}

// Layer-2 aggregate fused with residual + layernorm + val_w dot.
// One partial per wave (NO shared-address atomics — they serialize).
__global__ void agg2_final(const float* __restrict__ hw, const float* __restrict__ ssrc,
                           const float* __restrict__ sdst, const int* __restrict__ nbr,
                           const int* __restrict__ cnt, const float* __restrict__ b,
                           const float* __restrict__ x, const float* __restrict__ vw,
                           float* __restrict__ partial) {
    int wave = threadIdx.x >> 6;
    int lane = threadIdx.x & 63;
    int i = blockIdx.x * 4 + wave;
    int deg = min(cnt[i], MAXDEG);
    float sd = sdst[i];
    int j0 = 0, j1 = 0;
    float e0 = -1e30f, e1 = -1e30f;
    if (lane < deg) {
        j0 = nbr[i * MAXDEG + lane];
        float v = ssrc[j0] + sd;
        e0 = v > 0.f ? v : NEG_SLOPE * v;
    }
    if (lane + 64 < deg) {
        j1 = nbr[i * MAXDEG + lane + 64];
        float v = ssrc[j1] + sd;
        e1 = v > 0.f ? v : NEG_SLOPE * v;
    }
    float m = wave_reduce_max(fmaxf(e0, e1));
    float p0 = (lane < deg) ? expf(e0 - m) : 0.f;
    float p1 = (lane + 64 < deg) ? expf(e1 - m) : 0.f;
    float Z = wave_reduce_sum(p0 + p1);
    float acc = 0.f;
    int d0 = min(deg, 64);
    #pragma unroll 4
    for (int n = 0; n < d0; ++n) {
        int   j = __shfl(j0, n, 64);
        float p = __shfl(p0, n, 64);
        acc += p * hw[j * 64 + lane];
    }
    for (int n = 64; n < deg; ++n) {
        int   j = __shfl(j1, n - 64, 64);
        float p = __shfl(p1, n - 64, 64);
        acc += p * hw[j * 64 + lane];
    }
    acc = acc / Z + b[lane];
    // residual + layernorm (no affine) + dot with val_w
    float v = x[i * 64 + lane] + acc;
    float mu = wave_reduce_sum(v) * (1.f / 64.f);
    float d = v - mu;
    float var = wave_reduce_sum(d * d) * (1.f / 64.f);
    float ln = d * rsqrtf(var + LN_EPS);
    float part = wave_reduce_sum(ln * vw[lane]);
    if (lane == 0) partial[i] = part;
}

__global__ void reduce_out(const float* __restrict__ partial,
                           const float* __restrict__ val_b, float* __restrict__ out) {
    __shared__ float s[4];
    int wave = threadIdx.x >> 6;
    int lane = threadIdx.x & 63;
    float v = 0.f;
    for (int k = threadIdx.x; k < N; k += 256) v += partial[k];
    v = wave_reduce_sum(v);
    if (lane == 0) s[wave] = v;
    __syncthreads();
    if (threadIdx.x == 0) {
        float t = s[0] + s[1] + s[2] + s[3];
        out[0] = fmaxf(t * (1.f / (float)N) + val_b[0], 0.f);
    }
}

extern "C" void kernel_launch(void* const* d_in, const int* in_sizes, int n_in,
                              void* d_out, int out_size, void* d_ws, size_t ws_size,
                              hipStream_t stream) {
    const float* adj        = (const float*)d_in[0];
    const int*   timestep   = (const int*)  d_in[1];
    const float* arrivals   = (const float*)d_in[2];
    const float* departures = (const float*)d_in[3];
    const float* hard       = (const float*)d_in[4];
    // d_in[5] active_agents: unused by reference
    const float* emb_w1     = (const float*)d_in[6];
    const float* emb_b1     = (const float*)d_in[7];
    const float* emb_w2     = (const float*)d_in[8];
    const float* emb_b2     = (const float*)d_in[9];
    const float* gat_w      = (const float*)d_in[10];
    const float* gat_asrc   = (const float*)d_in[11];
    const float* gat_adst   = (const float*)d_in[12];
    const float* gat_b      = (const float*)d_in[13];
    const float* val_w      = (const float*)d_in[14];
    const float* val_b      = (const float*)d_in[15];

    char* ws = (char*)d_ws;
    int*   cnt     = (int*)  (ws);                    // 16 KB
    float* partial = (float*)(ws + 16384);            // 16 KB
    int*   nbr     = (int*)  (ws + 65536);            // 2 MB
    float* x       = (float*)(ws + (4u << 20));       // 1 MB
    float* h       = (float*)(ws + (5u << 20));       // 1 MB
    float* hw      = (float*)(ws + (6u << 20));       // 1 MB
    float* ssrc    = (float*)(ws + (7u << 20));       // 16 KB
    float* sdst    = (float*)(ws + (7u << 20) + 65536);

    hipMemsetAsync(cnt, 0, 16384, stream);

    build_nbr<<<256, 256, 0, stream>>>((const float4*)adj, cnt, nbr);
    emb_tr0<<<N / 4, 256, 0, stream>>>(timestep, arrivals, departures, hard,
                                       emb_w1, emb_b1, emb_w2, emb_b2,
                                       gat_w, gat_asrc, gat_adst,
                                       x, hw, ssrc, sdst);
    gat_aggregate<<<N / 4, 256, 0, stream>>>(hw, ssrc, sdst, nbr, cnt, gat_b, h, 1);
    for (int l = 1; l < 2; ++l) { /* layer 1 */ }
    gat_transform<<<N / 4, 256, 0, stream>>>(h, gat_w + 1 * 64 * 64,
                                             gat_asrc + 64, gat_adst + 64,
                                             hw, ssrc, sdst);
    gat_aggregate<<<N / 4, 256, 0, stream>>>(hw, ssrc, sdst, nbr, cnt, gat_b + 64, h, 1);
    gat_transform<<<N / 4, 256, 0, stream>>>(h, gat_w + 2 * 64 * 64,
                                             gat_asrc + 128, gat_adst + 128,
                                             hw, ssrc, sdst);
    agg2_final<<<N / 4, 256, 0, stream>>>(hw, ssrc, sdst, nbr, cnt, gat_b + 128,
                                          x, val_w, partial);
    reduce_out<<<1, 256, 0, stream>>>(partial, val_b, (float*)d_out);
}

// Round 3
// 196.629 us; speedup vs baseline: 1.3975x; 1.3975x over previous
//
#include <hip/hip_runtime.h>
#include <math.h>

#define N 4096
#define H 64
#define MAXDEG 128
#define NEG_SLOPE 0.2f
#define LN_EPS 1e-5f

__device__ __forceinline__ float wave_reduce_sum(float v) {
    #pragma unroll
    for (int m = 32; m >= 1; m >>= 1) v += __shfl_xor(v, m, 64);
    return v;
}
__device__ __forceinline__ float wave_reduce_max(float v) {
    #pragma unroll
    for (int m = 32; m >= 1; m >>= 1) v = fmaxf(v, __shfl_xor(v, m, 64));
    return v;
}

// Neighbor build: dest i's neighbors {j : adj[j][i] != 0} U {i}.
// 1M threads: thread owns colgroup cg (4 consecutive cols) x 4 rows.
// 4 unrolled float4 loads -> 4 outstanding 16B loads/thread at ~full occupancy.
__global__ void build_nbr(const float4* __restrict__ adj4,
                          int* __restrict__ cnt, int* __restrict__ nbr) {
    int t = blockIdx.x * blockDim.x + threadIdx.x;   // 1048576 threads
    int cg = t & 1023;
    int band = t >> 10;                              // 0..1023
    int i0 = cg * 4;
    int jbase = band * 4;
    float4 a[4];
    #pragma unroll
    for (int jj = 0; jj < 4; ++jj)
        a[jj] = adj4[(size_t)(jbase + jj) * 1024 + cg];
    #pragma unroll
    for (int jj = 0; jj < 4; ++jj) {
        int j = jbase + jj;
        if (a[jj].x != 0.f || j == i0)     { int p = atomicAdd(&cnt[i0],   1); if (p < MAXDEG) nbr[ i0      * MAXDEG + p] = j; }
        if (a[jj].y != 0.f || j == i0 + 1) { int p = atomicAdd(&cnt[i0+1], 1); if (p < MAXDEG) nbr[(i0 + 1) * MAXDEG + p] = j; }
        if (a[jj].z != 0.f || j == i0 + 2) { int p = atomicAdd(&cnt[i0+2], 1); if (p < MAXDEG) nbr[(i0 + 2) * MAXDEG + p] = j; }
        if (a[jj].w != 0.f || j == i0 + 3) { int p = atomicAdd(&cnt[i0+3], 1); if (p < MAXDEG) nbr[(i0 + 3) * MAXDEG + p] = j; }
    }
}

// Fused: embedding MLP (no nonlinearity) + layer-0 transform + scores.
__global__ void emb_tr0(const int* __restrict__ timestep,
                        const float* __restrict__ arr, const float* __restrict__ dep,
                        const float* __restrict__ hard,
                        const float* __restrict__ w1, const float* __restrict__ b1,
                        const float* __restrict__ w2, const float* __restrict__ b2,
                        const float* __restrict__ W0, const float* __restrict__ asrc,
                        const float* __restrict__ adst,
                        float* __restrict__ x, float* __restrict__ hw,
                        float* __restrict__ ssrc, float* __restrict__ sdst) {
    int wave = threadIdx.x >> 6;
    int lane = threadIdx.x & 63;
    int i = blockIdx.x * 4 + wave;
    float ts = (float)(*timestep);
    float pr = (ts - arr[i]) / (dep[i] - arr[i]);
    float hd = hard[i];
    float t = pr * w1[lane] + hd * w1[64 + lane] + b1[lane];
    float xv = b2[lane];
    #pragma unroll
    for (int k = 0; k < 64; ++k)
        xv += __shfl(t, k, 64) * w2[k * 64 + lane];
    x[i * 64 + lane] = xv;
    float acc = 0.f;
    #pragma unroll
    for (int k = 0; k < 64; ++k)
        acc += __shfl(xv, k, 64) * W0[k * 64 + lane];
    hw[i * 64 + lane] = acc;
    float s1 = wave_reduce_sum(acc * asrc[lane]);
    float s2 = wave_reduce_sum(acc * adst[lane]);
    if (lane == 0) { ssrc[i] = s1; sdst[i] = s2; }
}

// Fused: softmax-aggregate (layer l) + relu + transform (layer l+1) + scores.
// Reads hwin/ssin/sdin (all rows of prev layer), writes hwout/ssout/sdout.
__global__ void agg_tr(const float* __restrict__ hwin, const float* __restrict__ ssin,
                       const float* __restrict__ sdin, const int* __restrict__ nbr,
                       const int* __restrict__ cnt, const float* __restrict__ b,
                       const float* __restrict__ W, const float* __restrict__ asrc,
                       const float* __restrict__ adst,
                       float* __restrict__ hwout, float* __restrict__ ssout,
                       float* __restrict__ sdout) {
    int wave = threadIdx.x >> 6;
    int lane = threadIdx.x & 63;
    int i = blockIdx.x * 4 + wave;
    int deg = min(cnt[i], MAXDEG);
    float sd = sdin[i];
    int j0 = 0, j1 = 0;
    float e0 = -1e30f, e1 = -1e30f;
    if (lane < deg) {
        j0 = nbr[i * MAXDEG + lane];
        float v = ssin[j0] + sd;
        e0 = v > 0.f ? v : NEG_SLOPE * v;
    }
    if (lane + 64 < deg) {
        j1 = nbr[i * MAXDEG + lane + 64];
        float v = ssin[j1] + sd;
        e1 = v > 0.f ? v : NEG_SLOPE * v;
    }
    float m = wave_reduce_max(fmaxf(e0, e1));
    float p0 = (lane < deg) ? expf(e0 - m) : 0.f;
    float p1 = (lane + 64 < deg) ? expf(e1 - m) : 0.f;
    float Z = wave_reduce_sum(p0 + p1);
    float acc = 0.f;
    int d0 = min(deg, 64);
    #pragma unroll 4
    for (int n = 0; n < d0; ++n) {
        int   j = __shfl(j0, n, 64);
        float p = __shfl(p0, n, 64);
        acc += p * hwin[j * 64 + lane];
    }
    for (int n = 64; n < deg; ++n) {
        int   j = __shfl(j1, n - 64, 64);
        float p = __shfl(p1, n - 64, 64);
        acc += p * hwin[j * 64 + lane];
    }
    float hv = fmaxf(acc / Z + b[lane], 0.f);   // h + relu (between layers)
    // transform for next layer
    float tr = 0.f;
    #pragma unroll
    for (int k = 0; k < 64; ++k)
        tr += __shfl(hv, k, 64) * W[k * 64 + lane];
    hwout[i * 64 + lane] = tr;
    float s1 = wave_reduce_sum(tr * asrc[lane]);
    float s2 = wave_reduce_sum(tr * adst[lane]);
    if (lane == 0) { ssout[i] = s1; sdout[i] = s2; }
}

// Layer-2 aggregate fused with residual + layernorm + val_w dot.
__global__ void agg_final(const float* __restrict__ hwin, const float* __restrict__ ssin,
                          const float* __restrict__ sdin, const int* __restrict__ nbr,
                          const int* __restrict__ cnt, const float* __restrict__ b,
                          const float* __restrict__ x, const float* __restrict__ vw,
                          float* __restrict__ partial) {
    int wave = threadIdx.x >> 6;
    int lane = threadIdx.x & 63;
    int i = blockIdx.x * 4 + wave;
    int deg = min(cnt[i], MAXDEG);
    float sd = sdin[i];
    int j0 = 0, j1 = 0;
    float e0 = -1e30f, e1 = -1e30f;
    if (lane < deg) {
        j0 = nbr[i * MAXDEG + lane];
        float v = ssin[j0] + sd;
        e0 = v > 0.f ? v : NEG_SLOPE * v;
    }
    if (lane + 64 < deg) {
        j1 = nbr[i * MAXDEG + lane + 64];
        float v = ssin[j1] + sd;
        e1 = v > 0.f ? v : NEG_SLOPE * v;
    }
    float m = wave_reduce_max(fmaxf(e0, e1));
    float p0 = (lane < deg) ? expf(e0 - m) : 0.f;
    float p1 = (lane + 64 < deg) ? expf(e1 - m) : 0.f;
    float Z = wave_reduce_sum(p0 + p1);
    float acc = 0.f;
    int d0 = min(deg, 64);
    #pragma unroll 4
    for (int n = 0; n < d0; ++n) {
        int   j = __shfl(j0, n, 64);
        float p = __shfl(p0, n, 64);
        acc += p * hwin[j * 64 + lane];
    }
    for (int n = 64; n < deg; ++n) {
        int   j = __shfl(j1, n - 64, 64);
        float p = __shfl(p1, n - 64, 64);
        acc += p * hwin[j * 64 + lane];
    }
    acc = acc / Z + b[lane];
    float v = x[i * 64 + lane] + acc;
    float mu = wave_reduce_sum(v) * (1.f / 64.f);
    float d = v - mu;
    float var = wave_reduce_sum(d * d) * (1.f / 64.f);
    float ln = d * rsqrtf(var + LN_EPS);
    float part = wave_reduce_sum(ln * vw[lane]);
    if (lane == 0) partial[i] = part;
}

__global__ void reduce_out(const float* __restrict__ partial,
                           const float* __restrict__ val_b, float* __restrict__ out) {
    __shared__ float s[4];
    int wave = threadIdx.x >> 6;
    int lane = threadIdx.x & 63;
    float v = 0.f;
    for (int k = threadIdx.x; k < N; k += 256) v += partial[k];
    v = wave_reduce_sum(v);
    if (lane == 0) s[wave] = v;
    __syncthreads();
    if (threadIdx.x == 0) {
        float t = s[0] + s[1] + s[2] + s[3];
        out[0] = fmaxf(t * (1.f / (float)N) + val_b[0], 0.f);
    }
}

extern "C" void kernel_launch(void* const* d_in, const int* in_sizes, int n_in,
                              void* d_out, int out_size, void* d_ws, size_t ws_size,
                              hipStream_t stream) {
    const float* adj        = (const float*)d_in[0];
    const int*   timestep   = (const int*)  d_in[1];
    const float* arrivals   = (const float*)d_in[2];
    const float* departures = (const float*)d_in[3];
    const float* hard       = (const float*)d_in[4];
    // d_in[5] active_agents: unused by reference
    const float* emb_w1     = (const float*)d_in[6];
    const float* emb_b1     = (const float*)d_in[7];
    const float* emb_w2     = (const float*)d_in[8];
    const float* emb_b2     = (const float*)d_in[9];
    const float* gat_w      = (const float*)d_in[10];
    const float* gat_asrc   = (const float*)d_in[11];
    const float* gat_adst   = (const float*)d_in[12];
    const float* gat_b      = (const float*)d_in[13];
    const float* val_w      = (const float*)d_in[14];
    const float* val_b      = (const float*)d_in[15];

    char* ws = (char*)d_ws;
    int*   cnt     = (int*)  (ws);                    // 16 KB
    float* partial = (float*)(ws + 16384);            // 16 KB
    int*   nbr     = (int*)  (ws + 65536);            // 2 MB
    float* x       = (float*)(ws + (4u << 20));       // 1 MB
    float* hwA     = (float*)(ws + (5u << 20));       // 1 MB
    float* hwB     = (float*)(ws + (6u << 20));       // 1 MB
    float* ssA     = (float*)(ws + (7u << 20));
    float* sdA     = (float*)(ws + (7u << 20) + 65536);
    float* ssB     = (float*)(ws + (7u << 20) + 131072);
    float* sdB     = (float*)(ws + (7u << 20) + 196608);

    hipMemsetAsync(cnt, 0, 16384, stream);

    build_nbr<<<4096, 256, 0, stream>>>((const float4*)adj, cnt, nbr);
    emb_tr0<<<N / 4, 256, 0, stream>>>(timestep, arrivals, departures, hard,
                                       emb_w1, emb_b1, emb_w2, emb_b2,
                                       gat_w, gat_asrc, gat_adst,
                                       x, hwA, ssA, sdA);
    // layer 0 aggregate + layer 1 transform
    agg_tr<<<N / 4, 256, 0, stream>>>(hwA, ssA, sdA, nbr, cnt, gat_b,
                                      gat_w + 64 * 64, gat_asrc + 64, gat_adst + 64,
                                      hwB, ssB, sdB);
    // layer 1 aggregate + layer 2 transform
    agg_tr<<<N / 4, 256, 0, stream>>>(hwB, ssB, sdB, nbr, cnt, gat_b + 64,
                                      gat_w + 2 * 64 * 64, gat_asrc + 128, gat_adst + 128,
                                      hwA, ssA, sdA);
    // layer 2 aggregate + residual + LN + dot
    agg_final<<<N / 4, 256, 0, stream>>>(hwA, ssA, sdA, nbr, cnt, gat_b + 128,
                                         x, val_w, partial);
    reduce_out<<<1, 256, 0, stream>>>(partial, val_b, (float*)d_out);
}